// Round 17
// baseline (1375.548 us; speedup 1.0000x reference)
//
#include <hip/hip_runtime.h>
#include <hip/hip_bf16.h>
#include <math.h>

// Problem dims
#define NB 32
#define NS 128
#define NT 64
#define NV 32000
#define NE 256
#define NH 512

typedef short s16x8 __attribute__((ext_vector_type(8)));
typedef float f32x4 __attribute__((ext_vector_type(4)));
typedef unsigned u32x4 __attribute__((ext_vector_type(4)));

__device__ __forceinline__ unsigned short f2bf(float x) {
    union { float f; unsigned u; } v; v.f = x;
    unsigned r = v.u + 0x7FFFu + ((v.u >> 16) & 1u);   // RNE
    return (unsigned short)(r >> 16);
}
__device__ __forceinline__ float bf2f(short h) {
    union { unsigned u; float f; } x;
    x.u = ((unsigned)(unsigned short)h) << 16;
    return x.f;
}

// lgkm-only block barrier: drains LDS ops but leaves global ops in flight.
__device__ __forceinline__ void bar_lgkm() {
    asm volatile("s_waitcnt lgkmcnt(0)" ::: "memory");
    __builtin_amdgcn_sched_barrier(0);
    __builtin_amdgcn_s_barrier();
    __builtin_amdgcn_sched_barrier(0);
}

// ---- coherent (LLC-point) ops ----
__device__ __forceinline__ void st_pt(unsigned long long* p, unsigned pay, unsigned tag) {
    unsigned long long v = (unsigned long long)pay | ((unsigned long long)tag << 32);
    asm volatile("global_store_dwordx2 %0, %1, off sc0 sc1" :: "v"(p), "v"(v) : "memory");
}
__device__ __forceinline__ void st_coh32(unsigned* p, unsigned v) {
    asm volatile("global_store_dword %0, %1, off sc0 sc1" :: "v"(p), "v"(v) : "memory");
}
__device__ __forceinline__ unsigned ld_coh32(const unsigned* p) {
    unsigned v;
    asm volatile("global_load_dword %0, %1, off sc0 sc1\n\ts_waitcnt vmcnt(0)"
                 : "=v"(v) : "v"(p) : "memory");
    return v;
}
__device__ __forceinline__ void st_coh_x4(void* p, u32x4 v) {
    asm volatile("global_store_dwordx4 %0, %1, off sc0 sc1" :: "v"(p), "v"(v) : "memory");
}
// 64B contiguous coherent load (4 x 16B, one drain)
__device__ __forceinline__ void ld64_coh(const void* p, u32x4& a, u32x4& b, u32x4& c, u32x4& d) {
    asm volatile(
        "global_load_dwordx4 %0, %4, off sc0 sc1\n\t"
        "global_load_dwordx4 %1, %4, off offset:16 sc0 sc1\n\t"
        "global_load_dwordx4 %2, %4, off offset:32 sc0 sc1\n\t"
        "global_load_dwordx4 %3, %4, off offset:48 sc0 sc1\n\t"
        "s_waitcnt vmcnt(0)"
        : "=&v"(a), "=&v"(b), "=&v"(c), "=&v"(d)
        : "v"(p) : "memory");
}
__device__ __forceinline__ void ld8_pt(const unsigned long long* b0, unsigned long long* v) {
    unsigned long long v0, v1, v2, v3, v4, v5, v6, v7;
    asm volatile(
        "global_load_dwordx2 %0, %8, off sc0 sc1\n\t"
        "global_load_dwordx2 %1, %9, off sc0 sc1\n\t"
        "global_load_dwordx2 %2, %10, off sc0 sc1\n\t"
        "global_load_dwordx2 %3, %11, off sc0 sc1\n\t"
        "global_load_dwordx2 %4, %12, off sc0 sc1\n\t"
        "global_load_dwordx2 %5, %13, off sc0 sc1\n\t"
        "global_load_dwordx2 %6, %14, off sc0 sc1\n\t"
        "global_load_dwordx2 %7, %15, off sc0 sc1\n\t"
        "s_waitcnt vmcnt(0)"
        : "=&v"(v0), "=&v"(v1), "=&v"(v2), "=&v"(v3),
          "=&v"(v4), "=&v"(v5), "=&v"(v6), "=&v"(v7)
        : "v"(b0), "v"(b0 + 1024), "v"(b0 + 2048), "v"(b0 + 3072),
          "v"(b0 + 4096), "v"(b0 + 5120), "v"(b0 + 6144), "v"(b0 + 7168)
        : "memory");
    v[0] = v0; v[1] = v1; v[2] = v2; v[3] = v3;
    v[4] = v4; v[5] = v5; v[6] = v6; v[7] = v7;
}
__device__ __forceinline__ void ld3_pt(const unsigned long long* p0,
                                       const unsigned long long* p1,
                                       const unsigned long long* p2,
                                       unsigned long long& a, unsigned long long& b,
                                       unsigned long long& c) {
    asm volatile(
        "global_load_dwordx2 %0, %3, off sc0 sc1\n\t"
        "global_load_dwordx2 %1, %4, off sc0 sc1\n\t"
        "global_load_dwordx2 %2, %5, off sc0 sc1\n\t"
        "s_waitcnt vmcnt(0)"
        : "=&v"(a), "=&v"(b), "=&v"(c)
        : "v"(p0), "v"(p1), "v"(p2)
        : "memory");
}

// ---------------------------------------------------------------------------
// K0: pack W_s = [W_prev | Wh_g[:, :512] | Wh]  (512 x 1536) into MFMA frags
// ---------------------------------------------------------------------------
__global__ void build_wfrag_k(const float* __restrict__ Wp,
                              const float* __restrict__ Whg,
                              const float* __restrict__ Wh,
                              unsigned short* __restrict__ wfrag) {
    int blk = blockIdx.x;            // = ct*16 + kt ; ct<96, kt<16
    int lane = threadIdx.x;
    int ct = blk >> 4, kt = blk & 15;
    int c = ct * 16 + (lane & 15);
    int kb = kt * 32 + (lane >> 4) * 8;
    s16x8 v;
#pragma unroll
    for (int j = 0; j < 8; ++j) {
        int k = kb + j;
        float x;
        if (c < 512)       x = Wp[k * 512 + c];
        else if (c < 1024) x = Whg[k * 1024 + (c - 512)];
        else               x = Wh[k * 512 + (c - 1024)];
        v[j] = (short)f2bf(x);
    }
    ((s16x8*)wfrag)[blk * 64 + lane] = v;
}

// ---------------------------------------------------------------------------
// Generic MFMA bf16 GEMM, 128x128 tile, BK=32, 4 waves. MODE 0 (PRE), 1 (XP).
// ---------------------------------------------------------------------------
template<int MODE>
__global__ __launch_bounds__(256, 2) void gemm_mfma(
    const float* __restrict__ Af, const unsigned short* __restrict__ Abf,
    const int* __restrict__ gidx,
    const float* __restrict__ B0, const float* __restrict__ B1, const float* __restrict__ B2,
    const float* __restrict__ e0, const float* __restrict__ e1, const float* __restrict__ e2,
    const float* __restrict__ e3, const float* __restrict__ e4, const float* __restrict__ e5,
    void* __restrict__ O0v, void* __restrict__ O1v, void* __restrict__ O2v)
{
    constexpr int M   = (MODE == 0) ? 4096 : 2048;
    constexpr int K   = (MODE == 0) ? 1024 : 256;
    constexpr int LDA = (MODE == 0) ? 1024 : 256;
    constexpr int MB  = M / 128;

    const int bm = blockIdx.x % MB, bn = blockIdx.x / MB;
    const int m0 = bm * 128, n0 = bn * 128;

    const float* Bp; int ldb, coff;
    if constexpr (MODE == 0) {
        int sub = n0 >> 9;
        Bp   = (sub == 0) ? B0 : (sub == 1) ? B1 : B2;
        ldb  = (sub == 1) ? 1024 : 512;
        coff = n0 & 511;
    } else {
        if (n0 < 512) { Bp = B0; ldb = 1024; coff = n0; }
        else          { Bp = B1; ldb = 512;  coff = n0 - 512; }
    }

    __shared__ unsigned short As[128 * 40];
    __shared__ unsigned short Bs[128 * 40];

    const int tid = threadIdx.x, lane = tid & 63, w = tid >> 6;
    const int wr = w >> 1, wc = w & 1;
    const int k0f = (lane >> 4) * 8;
    const int rsel = lane & 15;

    f32x4 acc[4][4];
#pragma unroll
    for (int i = 0; i < 4; ++i)
#pragma unroll
        for (int j = 0; j < 4; ++j) { f32x4 z = {0.f, 0.f, 0.f, 0.f}; acc[i][j] = z; }

    for (int kt = 0; kt < K / 32; ++kt) {
        const int k0 = kt * 32;
        __syncthreads();
#pragma unroll
        for (int i = 0; i < 16; ++i) {
            int idx = tid + i * 256;
            int r = idx >> 5, k = idx & 31;
            unsigned short v;
            if constexpr (MODE == 1) {
                int g = gidx[m0 + r];
                v = f2bf(Af[(size_t)g * 256 + k0 + k]);
            } else {
                v = f2bf(Af[(size_t)(m0 + r) * LDA + k0 + k]);
            }
            As[r * 40 + k] = v;
        }
#pragma unroll
        for (int i = 0; i < 16; ++i) {
            int idx = tid + i * 256;
            int k = idx >> 7, c = idx & 127;
            Bs[c * 40 + k] = f2bf(Bp[(size_t)(k0 + k) * ldb + coff + c]);
        }
        __syncthreads();

        s16x8 af[4], bf[4];
#pragma unroll
        for (int i = 0; i < 4; ++i)
            af[i] = *(const s16x8*)&As[(wr * 64 + i * 16 + rsel) * 40 + k0f];
#pragma unroll
        for (int j = 0; j < 4; ++j)
            bf[j] = *(const s16x8*)&Bs[(wc * 64 + j * 16 + rsel) * 40 + k0f];
#pragma unroll
        for (int i = 0; i < 4; ++i)
#pragma unroll
            for (int j = 0; j < 4; ++j)
                acc[i][j] = __builtin_amdgcn_mfma_f32_16x16x32_bf16(af[i], bf[j], acc[i][j], 0, 0, 0);
    }

    const int rg = (lane >> 4) * 4;
#pragma unroll
    for (int i = 0; i < 4; ++i)
#pragma unroll
        for (int j = 0; j < 4; ++j) {
            int row0 = m0 + wr * 64 + i * 16 + rg;
            int col  = n0 + wc * 64 + j * 16 + rsel;
            if constexpr (MODE == 0) {
                int sub = col >> 9;
                if (sub == 0) {
                    unsigned short* Ta = (unsigned short*)O0v;
#pragma unroll
                    for (int r = 0; r < 4; ++r)
                        Ta[(size_t)(row0 + r) * 512 + col] = f2bf(tanhf(acc[i][j][r] + e0[col]));
                } else {
                    int h = col & 511;
                    int bb = row0 >> 7, s0 = row0 & 127;
                    unsigned long long pk = 0;
#pragma unroll
                    for (int r = 0; r < 4; ++r)
                        pk |= (unsigned long long)f2bf(acc[i][j][r]) << (16 * r);
                    unsigned short* dstp = (sub == 1) ? (unsigned short*)O1v : (unsigned short*)O2v;
                    *(unsigned long long*)&dstp[(size_t)((bb * 512 + h) * 128 + s0)] = pk;
                }
            } else {
                float* Of = (float*)O0v;
                float bias;
                if (col < 512) bias = e0[col] + e1[col] + e2[col];
                else { int h = col - 512; bias = e3[h] + e4[h] + e5[h]; }
#pragma unroll
                for (int r = 0; r < 4; ++r)
                    Of[(size_t)(row0 + r) * 1024 + col] = acc[i][j][r] + bias;
            }
        }
}

// ---------------------------------------------------------------------------
// Fused K3+K4: 256 blocks x 1024 threads.
//  blocks 0-31:   R14 tagged-dataflow scan. dh written t-major coherent.
//  block 32:      progress AGGREGATOR: min(prog[0..31]) -> single minprog word.
//  blocks 33-255: persistent OUT-GEMM consumers, chunked tn-major tile order
//                 (B-slice L2 reuse), gate = one broadcast minprog load.
// All 224 non-scan blocks also cooperatively pre-pack W_out into wpk first.
// ---------------------------------------------------------------------------
__global__ __launch_bounds__(1024) void fused_scan_out(
    const float* __restrict__ content, const float* __restrict__ sentiment,
    const float* __restrict__ b_prev,  const float* __restrict__ W_att,
    const unsigned short* __restrict__ Ta_bf,
    const unsigned short* __restrict__ hWcg_t,
    const unsigned short* __restrict__ hWc_t,
    const float* __restrict__ xgxs, const unsigned short* __restrict__ wfrag,
    unsigned long long* __restrict__ Spl, unsigned long long* __restrict__ Upl,
    unsigned short* __restrict__ dh, unsigned* __restrict__ prog,
    unsigned* __restrict__ packdone, unsigned* __restrict__ minprog,
    unsigned short* __restrict__ wpk,
    const float* __restrict__ W_out, const float* __restrict__ b_out,
    float* __restrict__ out)
{
    __shared__ __attribute__((aligned(16))) char smem[90624];
    const int tid = threadIdx.x, lane = tid & 63, w = tid >> 6;

    if (blockIdx.x < NB) {
        // =================== SCAN ROLE (R14 verbatim) ===================
        const int b = blockIdx.x;
        unsigned short* W_lds = (unsigned short*)smem;               // 48 KB
        unsigned short* S_lds = (unsigned short*)(smem + 49152);     // 33.5 KB
        float* tq = (float*)(smem + 83456);
        float* sc = (float*)(smem + 85504);
        float* al = (float*)(smem + 86016);
        float* cg = (float*)(smem + 86528);
        float* cs = (float*)(smem + 88576);

        {
            const s16x8* src = (const s16x8*)wfrag + (size_t)b * (3 * 16 * 64);
            s16x8* dst = (s16x8*)W_lds;
            for (int i = tid; i < 3 * 16 * 64; i += 1024) dst[i] = src[i];
        }
        float s_reg = 0.f, senth = 0.f, bprev_h = 0.f;
        if (tid < 512) {
            s_reg   = content[b * 512 + tid];
            senth   = 0.5f * sentiment[b * 512 + tid];
            bprev_h = b_prev[tid];
        }
        float wv[8];
        {
            const f32x4* wa = (const f32x4*)&W_att[lane * 8];
            f32x4 a0 = wa[0], a1 = wa[1];
#pragma unroll
            for (int j = 0; j < 4; ++j) { wv[j] = a0[j]; wv[4 + j] = a1[j]; }
        }
        const int kbase = (lane >> 4) * 8;
        const int mat = tid >> 9, hh = tid & 511;
        const s16x8* Mp = (const s16x8*)((mat ? hWc_t : hWcg_t) + ((size_t)(b * 512 + hh)) * 128);

        if (tid < 512) {
            float nsn = __shfl_down(s_reg, 1, 64);
            if (!(lane & 1)) {
                unsigned pay = (unsigned)f2bf(s_reg) | ((unsigned)f2bf(nsn) << 16);
                st_pt(&Spl[b * 256 + (tid >> 1)], pay, 1u);
            }
        }

        for (int t = 0; t < 64; ++t) {
            const unsigned want = (unsigned)(t + 1);
            float xg_pre = 0.f, xs_pre = 0.f;
            if (tid < 512) {
                xg_pre = xgxs[((size_t)b * 64 + t) * 1024 + tid];
                xs_pre = xgxs[((size_t)b * 64 + t) * 1024 + 512 + tid];
            }

            // Phase A: poll-stage all-batch S(t) into LDS
            {
                unsigned long long v[8];
                const unsigned long long* base = &Spl[tid];
                ld8_pt(base, v);
                for (;;) {
                    bool ok = true;
#pragma unroll
                    for (int ii = 0; ii < 8; ++ii) ok &= ((unsigned)(v[ii] >> 32) == want);
                    if (ok) break;
                    __builtin_amdgcn_s_sleep(1);
                    ld8_pt(base, v);
                }
#pragma unroll
                for (int ii = 0; ii < 8; ++ii) {
                    int idx = tid + ii * 1024;
                    int r = idx >> 8, c = (idx & 255) * 2;
                    *(unsigned*)&S_lds[r * 536 + c] = (unsigned)v[ii];
                }
            }
            bar_lgkm();

            if (w < 6) {
                const int mt = w & 1, ct = w >> 1;
                const int arow = mt * 16 + (lane & 15);
                f32x4 ae = {0.f, 0.f, 0.f, 0.f}, ao = {0.f, 0.f, 0.f, 0.f};
                const s16x8* wl = (const s16x8*)W_lds;
#pragma unroll
                for (int kt = 0; kt < 16; kt += 2) {
                    s16x8 a0 = *(const s16x8*)&S_lds[arow * 536 + kt * 32 + kbase];
                    s16x8 a1 = *(const s16x8*)&S_lds[arow * 536 + (kt + 1) * 32 + kbase];
                    ae = __builtin_amdgcn_mfma_f32_16x16x32_bf16(a0, wl[(ct * 16 + kt) * 64 + lane], ae, 0, 0, 0);
                    ao = __builtin_amdgcn_mfma_f32_16x16x32_bf16(a1, wl[(ct * 16 + kt + 1) * 64 + lane], ao, 0, 0, 0);
                }
                f32x4 a4 = ae + ao;
                const int cout = b * 48 + ct * 16 + (lane & 15);
                const int rbase = mt * 16 + (lane >> 4) * 4;
#pragma unroll
                for (int r = 0; r < 4; ++r)
                    st_pt(&Upl[(size_t)(rbase + r) * 1536 + cout], __float_as_uint(a4[r]), want);
            }

            float guv = 0.f, suv = 0.f;
            if (tid < 512) {
                unsigned long long u0, u1, u2;
                const unsigned long long* q0 = &Upl[b * 1536 + tid];
                const unsigned long long* q1 = &Upl[b * 1536 + 512 + tid];
                const unsigned long long* q2 = &Upl[b * 1536 + 1024 + tid];
                ld3_pt(q0, q1, q2, u0, u1, u2);
                while (((unsigned)(u0 >> 32) != want) | ((unsigned)(u1 >> 32) != want) |
                       ((unsigned)(u2 >> 32) != want)) {
                    __builtin_amdgcn_s_sleep(1);
                    ld3_pt(q0, q1, q2, u0, u1, u2);
                }
                float qv = __uint_as_float((unsigned)u0);
                guv = __uint_as_float((unsigned)u1);
                suv = __uint_as_float((unsigned)u2);
                tq[tid] = tanhf(qv + bprev_h);
            }
            bar_lgkm();

            {
                float tqv[8];
                const f32x4* tp = (const f32x4*)&tq[lane * 8];
                f32x4 t0 = tp[0], t1 = tp[1];
#pragma unroll
                for (int j = 0; j < 4; ++j) { tqv[j] = t0[j]; tqv[4 + j] = t1[j]; }
#pragma unroll
                for (int s8 = 0; s8 < 8; ++s8) {
                    int s = w * 8 + s8;
                    s16x8 tv = *(const s16x8*)&Ta_bf[((size_t)(b * 128 + s)) * 512 + lane * 8];
                    float a = 0.f;
#pragma unroll
                    for (int j = 0; j < 8; ++j) {
                        float ta = bf2f(tv[j]);
                        float num = ta + tqv[j];
                        float den = fmaf(ta, tqv[j], 1.0f);
                        a = fmaf(wv[j], num * __builtin_amdgcn_rcpf(den), a);
                    }
#pragma unroll
                    for (int off = 32; off; off >>= 1) a += __shfl_xor(a, off, 64);
                    if (lane == 0) sc[s] = a;
                }
            }
            bar_lgkm();
            if (w == 0) {
                float v0 = sc[lane], v1 = sc[lane + 64];
                float m = fmaxf(v0, v1);
#pragma unroll
                for (int off = 32; off; off >>= 1) m = fmaxf(m, __shfl_xor(m, off, 64));
                float p0 = __expf(v0 - m), p1 = __expf(v1 - m);
                float sm = p0 + p1;
#pragma unroll
                for (int off = 32; off; off >>= 1) sm += __shfl_xor(sm, off, 64);
                float inv = __builtin_amdgcn_rcpf(sm);
                al[lane] = p0 * inv; al[lane + 64] = p1 * inv;
            }
            bar_lgkm();
            {
                float a0 = 0.f, a1 = 0.f;
#pragma unroll
                for (int q = 0; q < 16; ++q) {
                    s16x8 v = Mp[q];
#pragma unroll
                    for (int j = 0; j < 8; j += 2) {
                        a0 = fmaf(al[q * 8 + j],     bf2f(v[j]),     a0);
                        a1 = fmaf(al[q * 8 + j + 1], bf2f(v[j + 1]), a1);
                    }
                }
                if (mat) cs[hh] = a0 + a1; else cg[hh] = a0 + a1;
            }
            bar_lgkm();
            if (tid < 512) {
                int h = tid;
                float g  = guv + xg_pre + cg[h];
                float r  = __builtin_amdgcn_rcpf(1.0f + __expf(-g));
                float sp = suv + xs_pre + cs[h];
                float e  = __expf(2.0f * sp);
                float st = 1.0f - 2.0f * __builtin_amdgcn_rcpf(e + 1.0f);
                float ns = s_reg + r * (st - s_reg);
                s_reg = ns;
                float dv = ns + senth;
                float dvn = __shfl_down(dv, 1, 64);
                if (!(lane & 1)) {
                    unsigned pk = (unsigned)f2bf(dv) | ((unsigned)f2bf(dvn) << 16);
                    st_coh32((unsigned*)dh + ((((size_t)t * 32 + b) * 512 + h) >> 1), pk);
                }
                if (t < 63) {
                    float nsn = __shfl_down(ns, 1, 64);
                    if (!(lane & 1)) {
                        unsigned pay = (unsigned)f2bf(ns) | ((unsigned)f2bf(nsn) << 16);
                        st_pt(&Spl[b * 256 + (h >> 1)], pay, (unsigned)(t + 2));
                    }
                }
            }
            if ((t & 7) == 7) asm volatile("s_waitcnt vmcnt(0)" ::: "memory");
            bar_lgkm();
            if ((t & 7) == 7 && tid == 0)
                st_coh32(&prog[b * 16], (unsigned)(t + 1));
        }
    } else {
        // =================== NON-SCAN ROLES ===================
        const int k4 = blockIdx.x - NB;                        // 0..223
        unsigned short* As = (unsigned short*)smem;            // [256][136]

        // ---- (a) cooperative W_out pre-pack into MFMA B fragments ----
        for (int u = k4 * 16 + w; u < 32000; u += 224 * 16) {
            int ct = u >> 4, kt = u & 15;
            int c = ct * 16 + (lane & 15);
            int kb = kt * 32 + (lane >> 4) * 8;
            s16x8 v;
#pragma unroll
            for (int j = 0; j < 8; ++j)
                v[j] = (short)f2bf(W_out[(size_t)(kb + j) * 32000 + c]);
            union { s16x8 s; u32x4 u4; } cv; cv.s = v;
            st_coh_x4(&wpk[(size_t)u * 512 + (size_t)lane * 8], cv.u4);
        }
        asm volatile("s_waitcnt vmcnt(0)" ::: "memory");
        __syncthreads();
        if (tid == 0)
            __hip_atomic_fetch_add(packdone, 1u, __ATOMIC_RELAXED, __HIP_MEMORY_SCOPE_AGENT);

        if (k4 == 0) {
            // =============== AGGREGATOR BLOCK ===============
            if (w == 0) {
                for (;;) {
                    unsigned v = 0xFFFFFFFFu;
                    if (lane < 32) v = ld_coh32(&prog[lane * 16]);
                    unsigned mn = v;
#pragma unroll
                    for (int off = 32; off; off >>= 1)
                        mn = min(mn, (unsigned)__shfl_xor((int)mn, off, 64));
                    if (lane == 0) st_coh32(minprog, mn);
                    if (mn >= 64u) break;
                    __builtin_amdgcn_s_sleep(4);
                }
            }
            return;   // waves exit (no further block barriers)
        }

        // =============== CONSUMER BLOCKS (k4 = 1..223) ===============
        if (w == 0 && lane == 0) {
            while (__hip_atomic_load(packdone, __ATOMIC_RELAXED, __HIP_MEMORY_SCOPE_AGENT) < 224u)
                __builtin_amdgcn_s_sleep(16);
        }
        __syncthreads();
        __builtin_amdgcn_fence(__ATOMIC_ACQUIRE, "agent");   // ONE L2 invalidate
        __syncthreads();

        const int wr = w >> 2, wc = w & 3;
        const int k0f = (lane >> 4) * 8;
        const int rsel = lane & 15;
        const int rg = (lane >> 4) * 4;
        const int ar4 = tid >> 2, aq = tid & 3;
        const s16x8* wpk8 = (const s16x8*)wpk;
        const int c = k4 - 1;                                 // 0..222
        const int jstart = (c * 1000) / 223;
        const int jend   = ((c + 1) * 1000) / 223;

        for (int j = jstart; j < jend; ++j) {
            const int tn = j >> 3, tm = j & 7;                // tn-major: B-slice reuse
            const unsigned need = (unsigned)(tm * 8 + 8);
            if (w == 0) {
                while (ld_coh32(minprog) < need)
                    __builtin_amdgcn_s_sleep(32);
            }
            __syncthreads();

            const int m0 = tm * 256, n0 = tn * 256;
            f32x4 acc[4][4];
#pragma unroll
            for (int i = 0; i < 4; ++i)
#pragma unroll
                for (int jj = 0; jj < 4; ++jj) { f32x4 z = {0.f, 0.f, 0.f, 0.f}; acc[i][jj] = z; }

#pragma unroll
            for (int kq = 0; kq < 4; ++kq) {
                __syncthreads();
                {   // stage 4 k-tiles of A: 64B contiguous coherent per thread
                    const unsigned short* sp = &dh[(size_t)(m0 + ar4) * 512 + kq * 128 + aq * 32];
                    u32x4 a0, a1, a2, a3;
                    ld64_coh(sp, a0, a1, a2, a3);
                    int base = ar4 * 136 + aq * 32;
                    *(u32x4*)&As[base]      = a0;
                    *(u32x4*)&As[base + 8]  = a1;
                    *(u32x4*)&As[base + 16] = a2;
                    *(u32x4*)&As[base + 24] = a3;
                }
                __syncthreads();
#pragma unroll
                for (int kk = 0; kk < 4; ++kk) {
                    const int kt = kq * 4 + kk;
                    s16x8 bfr[4], af[4];
#pragma unroll
                    for (int jj = 0; jj < 4; ++jj)
                        bfr[jj] = wpk8[(size_t)(((tn * 16 + wc * 4 + jj) * 16 + kt)) * 64 + lane];
#pragma unroll
                    for (int i = 0; i < 4; ++i)
                        af[i] = *(const s16x8*)&As[(wr * 64 + i * 16 + rsel) * 136 + kk * 32 + k0f];
#pragma unroll
                    for (int i = 0; i < 4; ++i)
#pragma unroll
                        for (int jj = 0; jj < 4; ++jj)
                            acc[i][jj] = __builtin_amdgcn_mfma_f32_16x16x32_bf16(af[i], bfr[jj], acc[i][jj], 0, 0, 0);
                }
            }

            // epilogue: trow = t*32 + b -> out[(b*64+t)][col]
#pragma unroll
            for (int i = 0; i < 4; ++i)
#pragma unroll
                for (int jj = 0; jj < 4; ++jj) {
                    int trow0 = m0 + wr * 64 + i * 16 + rg;
                    int col   = n0 + wc * 64 + jj * 16 + rsel;
                    float bb_ = 1.5f * b_out[col];
#pragma unroll
                    for (int r = 0; r < 4; ++r) {
                        int trow = trow0 + r;
                        int bb = trow & 31, tt = trow >> 5;
                        out[(size_t)(bb * 64 + tt) * 32000 + col] = acc[i][jj][r] + bb_;
                    }
                }
        }
    }
}

// ---------------------------------------------------------------------------
extern "C" void kernel_launch(void* const* d_in, const int* in_sizes, int n_in,
                              void* d_out, int out_size, void* d_ws, size_t ws_size,
                              hipStream_t stream) {
    const float* content  = (const float*)d_in[0];
    const float* sentiment= (const float*)d_in[1];
    const float* hiddens  = (const float*)d_in[2];
    const int*   target   = (const int*)  d_in[3];
    const float* embed    = (const float*)d_in[4];
    const float* W_enc = (const float*)d_in[5];  const float* b_enc = (const float*)d_in[6];
    const float* W_prev= (const float*)d_in[7];  const float* b_prev= (const float*)d_in[8];
    const float* W_att = (const float*)d_in[9];  /* b_att (d_in[10]) cancels in softmax */
    const float* Wi_g  = (const float*)d_in[11]; const float* bi_g  = (const float*)d_in[12];
    const float* Wh_g  = (const float*)d_in[13]; const float* bh_g  = (const float*)d_in[14];
    const float* Wc_g  = (const float*)d_in[15]; const float* bc_g  = (const float*)d_in[16];
    const float* Wi    = (const float*)d_in[17]; const float* bi    = (const float*)d_in[18];
    const float* Wh    = (const float*)d_in[19]; const float* bh    = (const float*)d_in[20];
    const float* Wc    = (const float*)d_in[21]; const float* bc    = (const float*)d_in[22];
    const float* W_out = (const float*)d_in[23]; const float* b_out = (const float*)d_in[24];
    float* out = (float*)d_out;

    // workspace layout (bytes)
    char* ws = (char*)d_ws;
    unsigned short* wfrag = (unsigned short*)ws;                       // 1.5 MB @0
    unsigned long long* Spl = (unsigned long long*)(ws + 0x180000);    // 64 KB  (pay,tag)
    unsigned long long* Upl = (unsigned long long*)(ws + 0x190000);    // 384 KB (pay,tag)
    unsigned* prog = (unsigned*)(ws + 0x1F0000);                       // 2 KB progress flags
    unsigned* packdone = (unsigned*)(ws + 0x1F0800);                   // 4 B
    unsigned* minprog  = (unsigned*)(ws + 0x1F0900);                   // 4 B (own line)
    unsigned short* Ta_bf   = (unsigned short*)(ws + 0x200000);        // 4 MB [4096][512]
    unsigned short* hWcg_t  = (unsigned short*)(ws + 0x600000);        // 4 MB [32][512][128]
    unsigned short* hWc_t   = (unsigned short*)(ws + 0xA00000);        // 4 MB
    float* xgxs     = (float*)(ws + 0xE00000);                         // 8 MB [2048][1024]
    unsigned short* dh      = (unsigned short*)(ws + 0x1600000);       // 2 MB t-major [64*32][512]
    unsigned short* wpk     = (unsigned short*)(ws + 0x1800000);       // 32.75 MB packed W_out

    // zero tag planes + progress flags + packdone + minprog every launch
    hipMemsetAsync(ws + 0x180000, 0, 0x71000, stream);

    // K0: pack recurrent weight fragments
    build_wfrag_k<<<96 * 16, 64, 0, stream>>>(W_prev, Wh_g, Wh, wfrag);

    // K1: PRE gemm -> Ta_bf, hWcg_t/hWc_t
    gemm_mfma<0><<<32 * 12, 256, 0, stream>>>(
        hiddens, nullptr, nullptr, W_enc, Wc_g, Wc,
        b_enc, nullptr, nullptr, nullptr, nullptr, nullptr,
        (void*)Ta_bf, (void*)hWcg_t, (void*)hWc_t);

    // K2: XP gemm -> xgxs
    gemm_mfma<1><<<16 * 8, 256, 0, stream>>>(
        embed, nullptr, target, Wi_g, Wi, nullptr,
        bi_g, bh_g, bc_g, bi, bh, bc,
        (void*)xgxs, nullptr, nullptr);

    // K3+K4 fused: scan (0-31) + aggregator (32) + tile consumers (33-255)
    fused_scan_out<<<256, 1024, 0, stream>>>(
        content, sentiment, b_prev, W_att, Ta_bf, hWcg_t, hWc_t,
        xgxs, wfrag, Spl, Upl, dh, prog, packdone, minprog, wpk,
        W_out, b_out, out);

    (void)in_sizes; (void)n_in; (void)out_size; (void)ws_size;
}

// Round 18
// 1259.895 us; speedup vs baseline: 1.0918x; 1.0918x over previous
//
#include <hip/hip_runtime.h>
#include <hip/hip_bf16.h>
#include <math.h>

// Problem dims
#define NB 32
#define NS 128
#define NT 64
#define NV 32000
#define NE 256
#define NH 512

typedef short s16x8 __attribute__((ext_vector_type(8)));
typedef float f32x4 __attribute__((ext_vector_type(4)));
typedef unsigned u32x4 __attribute__((ext_vector_type(4)));

__device__ __forceinline__ unsigned short f2bf(float x) {
    union { float f; unsigned u; } v; v.f = x;
    unsigned r = v.u + 0x7FFFu + ((v.u >> 16) & 1u);   // RNE
    return (unsigned short)(r >> 16);
}
__device__ __forceinline__ float bf2f(short h) {
    union { unsigned u; float f; } x;
    x.u = ((unsigned)(unsigned short)h) << 16;
    return x.f;
}

// lgkm-only block barrier: drains LDS ops but leaves global ops in flight.
__device__ __forceinline__ void bar_lgkm() {
    asm volatile("s_waitcnt lgkmcnt(0)" ::: "memory");
    __builtin_amdgcn_sched_barrier(0);
    __builtin_amdgcn_s_barrier();
    __builtin_amdgcn_sched_barrier(0);
}

// ---- coherent (LLC-point) ops ----
__device__ __forceinline__ void st_pt(unsigned long long* p, unsigned pay, unsigned tag) {
    unsigned long long v = (unsigned long long)pay | ((unsigned long long)tag << 32);
    asm volatile("global_store_dwordx2 %0, %1, off sc0 sc1" :: "v"(p), "v"(v) : "memory");
}
__device__ __forceinline__ void st_coh32(unsigned* p, unsigned v) {
    asm volatile("global_store_dword %0, %1, off sc0 sc1" :: "v"(p), "v"(v) : "memory");
}
__device__ __forceinline__ unsigned ld_coh32(const unsigned* p) {
    unsigned v;
    asm volatile("global_load_dword %0, %1, off sc0 sc1\n\ts_waitcnt vmcnt(0)"
                 : "=v"(v) : "v"(p) : "memory");
    return v;
}
__device__ __forceinline__ void st_coh_x4(void* p, u32x4 v) {
    asm volatile("global_store_dwordx4 %0, %1, off sc0 sc1" :: "v"(p), "v"(v) : "memory");
}
// 64B contiguous coherent load (4 x 16B, one drain)
__device__ __forceinline__ void ld64_coh(const void* p, u32x4& a, u32x4& b, u32x4& c, u32x4& d) {
    asm volatile(
        "global_load_dwordx4 %0, %4, off sc0 sc1\n\t"
        "global_load_dwordx4 %1, %4, off offset:16 sc0 sc1\n\t"
        "global_load_dwordx4 %2, %4, off offset:32 sc0 sc1\n\t"
        "global_load_dwordx4 %3, %4, off offset:48 sc0 sc1\n\t"
        "s_waitcnt vmcnt(0)"
        : "=&v"(a), "=&v"(b), "=&v"(c), "=&v"(d)
        : "v"(p) : "memory");
}
__device__ __forceinline__ void ld8_pt(const unsigned long long* b0, unsigned long long* v) {
    unsigned long long v0, v1, v2, v3, v4, v5, v6, v7;
    asm volatile(
        "global_load_dwordx2 %0, %8, off sc0 sc1\n\t"
        "global_load_dwordx2 %1, %9, off sc0 sc1\n\t"
        "global_load_dwordx2 %2, %10, off sc0 sc1\n\t"
        "global_load_dwordx2 %3, %11, off sc0 sc1\n\t"
        "global_load_dwordx2 %4, %12, off sc0 sc1\n\t"
        "global_load_dwordx2 %5, %13, off sc0 sc1\n\t"
        "global_load_dwordx2 %6, %14, off sc0 sc1\n\t"
        "global_load_dwordx2 %7, %15, off sc0 sc1\n\t"
        "s_waitcnt vmcnt(0)"
        : "=&v"(v0), "=&v"(v1), "=&v"(v2), "=&v"(v3),
          "=&v"(v4), "=&v"(v5), "=&v"(v6), "=&v"(v7)
        : "v"(b0), "v"(b0 + 1024), "v"(b0 + 2048), "v"(b0 + 3072),
          "v"(b0 + 4096), "v"(b0 + 5120), "v"(b0 + 6144), "v"(b0 + 7168)
        : "memory");
    v[0] = v0; v[1] = v1; v[2] = v2; v[3] = v3;
    v[4] = v4; v[5] = v5; v[6] = v6; v[7] = v7;
}
__device__ __forceinline__ void ld3_pt(const unsigned long long* p0,
                                       const unsigned long long* p1,
                                       const unsigned long long* p2,
                                       unsigned long long& a, unsigned long long& b,
                                       unsigned long long& c) {
    asm volatile(
        "global_load_dwordx2 %0, %3, off sc0 sc1\n\t"
        "global_load_dwordx2 %1, %4, off sc0 sc1\n\t"
        "global_load_dwordx2 %2, %5, off sc0 sc1\n\t"
        "s_waitcnt vmcnt(0)"
        : "=&v"(a), "=&v"(b), "=&v"(c)
        : "v"(p0), "v"(p1), "v"(p2)
        : "memory");
}

// ---------------------------------------------------------------------------
// Shared MFMA GEMM body (128x128 tile, BK=32, 4 waves). MODE 0 (PRE), 1 (XP).
// ---------------------------------------------------------------------------
template<int MODE>
__device__ __forceinline__ void gemm_body(
    int bidx, unsigned short* As, unsigned short* Bs,
    const float* __restrict__ Af, const int* __restrict__ gidx,
    const float* __restrict__ B0, const float* __restrict__ B1, const float* __restrict__ B2,
    const float* __restrict__ e0, const float* __restrict__ e1, const float* __restrict__ e2,
    const float* __restrict__ e3, const float* __restrict__ e4, const float* __restrict__ e5,
    void* __restrict__ O0v, void* __restrict__ O1v, void* __restrict__ O2v)
{
    constexpr int M   = (MODE == 0) ? 4096 : 2048;
    constexpr int K   = (MODE == 0) ? 1024 : 256;
    constexpr int LDA = (MODE == 0) ? 1024 : 256;
    constexpr int MB  = M / 128;

    const int bm = bidx % MB, bn = bidx / MB;
    const int m0 = bm * 128, n0 = bn * 128;

    const float* Bp; int ldb, coff;
    if constexpr (MODE == 0) {
        int sub = n0 >> 9;
        Bp   = (sub == 0) ? B0 : (sub == 1) ? B1 : B2;
        ldb  = (sub == 1) ? 1024 : 512;
        coff = n0 & 511;
    } else {
        if (n0 < 512) { Bp = B0; ldb = 1024; coff = n0; }
        else          { Bp = B1; ldb = 512;  coff = n0 - 512; }
    }

    const int tid = threadIdx.x, lane = tid & 63, w = tid >> 6;
    const int wr = w >> 1, wc = w & 1;
    const int k0f = (lane >> 4) * 8;
    const int rsel = lane & 15;

    f32x4 acc[4][4];
#pragma unroll
    for (int i = 0; i < 4; ++i)
#pragma unroll
        for (int j = 0; j < 4; ++j) { f32x4 z = {0.f, 0.f, 0.f, 0.f}; acc[i][j] = z; }

    for (int kt = 0; kt < K / 32; ++kt) {
        const int k0 = kt * 32;
        __syncthreads();
#pragma unroll
        for (int i = 0; i < 16; ++i) {
            int idx = tid + i * 256;
            int r = idx >> 5, k = idx & 31;
            unsigned short v;
            if constexpr (MODE == 1) {
                int g = gidx[m0 + r];
                v = f2bf(Af[(size_t)g * 256 + k0 + k]);
            } else {
                v = f2bf(Af[(size_t)(m0 + r) * LDA + k0 + k]);
            }
            As[r * 40 + k] = v;
        }
#pragma unroll
        for (int i = 0; i < 16; ++i) {
            int idx = tid + i * 256;
            int k = idx >> 7, c = idx & 127;
            Bs[c * 40 + k] = f2bf(Bp[(size_t)(k0 + k) * ldb + coff + c]);
        }
        __syncthreads();

        s16x8 af[4], bf[4];
#pragma unroll
        for (int i = 0; i < 4; ++i)
            af[i] = *(const s16x8*)&As[(wr * 64 + i * 16 + rsel) * 40 + k0f];
#pragma unroll
        for (int j = 0; j < 4; ++j)
            bf[j] = *(const s16x8*)&Bs[(wc * 64 + j * 16 + rsel) * 40 + k0f];
#pragma unroll
        for (int i = 0; i < 4; ++i)
#pragma unroll
            for (int j = 0; j < 4; ++j)
                acc[i][j] = __builtin_amdgcn_mfma_f32_16x16x32_bf16(af[i], bf[j], acc[i][j], 0, 0, 0);
    }

    const int rg = (lane >> 4) * 4;
#pragma unroll
    for (int i = 0; i < 4; ++i)
#pragma unroll
        for (int j = 0; j < 4; ++j) {
            int row0 = m0 + wr * 64 + i * 16 + rg;
            int col  = n0 + wc * 64 + j * 16 + rsel;
            if constexpr (MODE == 0) {
                int sub = col >> 9;
                if (sub == 0) {
                    unsigned short* Ta = (unsigned short*)O0v;
#pragma unroll
                    for (int r = 0; r < 4; ++r)
                        Ta[(size_t)(row0 + r) * 512 + col] = f2bf(tanhf(acc[i][j][r] + e0[col]));
                } else {
                    int h = col & 511;
                    int bb = row0 >> 7, s0 = row0 & 127;
                    unsigned long long pk = 0;
#pragma unroll
                    for (int r = 0; r < 4; ++r)
                        pk |= (unsigned long long)f2bf(acc[i][j][r]) << (16 * r);
                    unsigned short* dstp = (sub == 1) ? (unsigned short*)O1v : (unsigned short*)O2v;
                    *(unsigned long long*)&dstp[(size_t)((bb * 512 + h) * 128 + s0)] = pk;
                }
            } else {
                float* Of = (float*)O0v;
                float bias;
                if (col < 512) bias = e0[col] + e1[col] + e2[col];
                else { int h = col - 512; bias = e3[h] + e4[h] + e5[h]; }
#pragma unroll
                for (int r = 0; r < 4; ++r)
                    Of[(size_t)(row0 + r) * 1024 + col] = acc[i][j][r] + bias;
            }
        }
}

// ---------------------------------------------------------------------------
// Pre-kernel: K1 (384 blocks) + K2 (128 blocks) + K0 (384 blocks, 4 units ea)
// fused into one launch — K0/K2 run concurrent with K1, 2 launch gaps saved.
// ---------------------------------------------------------------------------
__global__ __launch_bounds__(256, 2) void pre_kernel(
    const float* __restrict__ hiddens,
    const float* __restrict__ W_enc, const float* __restrict__ Wc_g, const float* __restrict__ Wc,
    const float* __restrict__ b_enc,
    unsigned short* __restrict__ Ta_bf, unsigned short* __restrict__ hWcg_t,
    unsigned short* __restrict__ hWc_t,
    const float* __restrict__ embed, const int* __restrict__ target,
    const float* __restrict__ Wi_g, const float* __restrict__ Wi,
    const float* __restrict__ bi_g, const float* __restrict__ bh_g, const float* __restrict__ bc_g,
    const float* __restrict__ bi, const float* __restrict__ bh, const float* __restrict__ bc,
    float* __restrict__ xgxs,
    const float* __restrict__ Wp, const float* __restrict__ Whg, const float* __restrict__ Wh,
    unsigned short* __restrict__ wfrag)
{
    __shared__ unsigned short As[128 * 40];
    __shared__ unsigned short Bs[128 * 40];
    const int bid = blockIdx.x;

    if (bid < 384) {
        gemm_body<0>(bid, As, Bs, hiddens, nullptr, W_enc, Wc_g, Wc,
                     b_enc, nullptr, nullptr, nullptr, nullptr, nullptr,
                     (void*)Ta_bf, (void*)hWcg_t, (void*)hWc_t);
    } else if (bid < 512) {
        gemm_body<1>(bid - 384, As, Bs, embed, target, Wi_g, Wi, nullptr,
                     bi_g, bh_g, bc_g, bi, bh, bc,
                     (void*)xgxs, nullptr, nullptr);
    } else {
        // K0: 4 units per block (unit = ct*16 + kt)
        const int lane = threadIdx.x & 63;
        const int unit = (bid - 512) * 4 + (threadIdx.x >> 6);
        int ct = unit >> 4, kt = unit & 15;
        int c = ct * 16 + (lane & 15);
        int kb = kt * 32 + (lane >> 4) * 8;
        s16x8 v;
#pragma unroll
        for (int j = 0; j < 8; ++j) {
            int k = kb + j;
            float x;
            if (c < 512)       x = Wp[k * 512 + c];
            else if (c < 1024) x = Whg[k * 1024 + (c - 512)];
            else               x = Wh[k * 512 + (c - 1024)];
            v[j] = (short)f2bf(x);
        }
        ((s16x8*)wfrag)[unit * 64 + lane] = v;
    }
}

// ---------------------------------------------------------------------------
// Fused K3+K4 (R16 verbatim, consumer poll sleep 32->64): 256 blocks x 1024.
//  blocks 0-31:   tagged-dataflow scan. dh written t-major coherent.
//  blocks 32-255: (a) cooperative W_out pre-pack; (b) persistent OUT-GEMM,
//                 interleaved tm-major tile order, per-block prog-flag gate.
// ---------------------------------------------------------------------------
__global__ __launch_bounds__(1024) void fused_scan_out(
    const float* __restrict__ content, const float* __restrict__ sentiment,
    const float* __restrict__ b_prev,  const float* __restrict__ W_att,
    const unsigned short* __restrict__ Ta_bf,
    const unsigned short* __restrict__ hWcg_t,
    const unsigned short* __restrict__ hWc_t,
    const float* __restrict__ xgxs, const unsigned short* __restrict__ wfrag,
    unsigned long long* __restrict__ Spl, unsigned long long* __restrict__ Upl,
    unsigned short* __restrict__ dh, unsigned* __restrict__ prog,
    unsigned* __restrict__ packdone, unsigned short* __restrict__ wpk,
    const float* __restrict__ W_out, const float* __restrict__ b_out,
    float* __restrict__ out)
{
    __shared__ __attribute__((aligned(16))) char smem[90624];
    const int tid = threadIdx.x, lane = tid & 63, w = tid >> 6;

    if (blockIdx.x < NB) {
        // =================== SCAN ROLE ===================
        const int b = blockIdx.x;
        unsigned short* W_lds = (unsigned short*)smem;               // 48 KB
        unsigned short* S_lds = (unsigned short*)(smem + 49152);     // 33.5 KB
        float* tq = (float*)(smem + 83456);
        float* sc = (float*)(smem + 85504);
        float* al = (float*)(smem + 86016);
        float* cg = (float*)(smem + 86528);
        float* cs = (float*)(smem + 88576);

        {
            const s16x8* src = (const s16x8*)wfrag + (size_t)b * (3 * 16 * 64);
            s16x8* dst = (s16x8*)W_lds;
            for (int i = tid; i < 3 * 16 * 64; i += 1024) dst[i] = src[i];
        }
        float s_reg = 0.f, senth = 0.f, bprev_h = 0.f;
        if (tid < 512) {
            s_reg   = content[b * 512 + tid];
            senth   = 0.5f * sentiment[b * 512 + tid];
            bprev_h = b_prev[tid];
        }
        float wv[8];
        {
            const f32x4* wa = (const f32x4*)&W_att[lane * 8];
            f32x4 a0 = wa[0], a1 = wa[1];
#pragma unroll
            for (int j = 0; j < 4; ++j) { wv[j] = a0[j]; wv[4 + j] = a1[j]; }
        }
        const int kbase = (lane >> 4) * 8;
        const int mat = tid >> 9, hh = tid & 511;
        const s16x8* Mp = (const s16x8*)((mat ? hWc_t : hWcg_t) + ((size_t)(b * 512 + hh)) * 128);

        if (tid < 512) {
            float nsn = __shfl_down(s_reg, 1, 64);
            if (!(lane & 1)) {
                unsigned pay = (unsigned)f2bf(s_reg) | ((unsigned)f2bf(nsn) << 16);
                st_pt(&Spl[b * 256 + (tid >> 1)], pay, 1u);
            }
        }

        for (int t = 0; t < 64; ++t) {
            const unsigned want = (unsigned)(t + 1);
            float xg_pre = 0.f, xs_pre = 0.f;
            if (tid < 512) {
                xg_pre = xgxs[((size_t)b * 64 + t) * 1024 + tid];
                xs_pre = xgxs[((size_t)b * 64 + t) * 1024 + 512 + tid];
            }

            // Phase A: poll-stage all-batch S(t) into LDS
            {
                unsigned long long v[8];
                const unsigned long long* base = &Spl[tid];
                ld8_pt(base, v);
                for (;;) {
                    bool ok = true;
#pragma unroll
                    for (int ii = 0; ii < 8; ++ii) ok &= ((unsigned)(v[ii] >> 32) == want);
                    if (ok) break;
                    __builtin_amdgcn_s_sleep(1);
                    ld8_pt(base, v);
                }
#pragma unroll
                for (int ii = 0; ii < 8; ++ii) {
                    int idx = tid + ii * 1024;
                    int r = idx >> 8, c = (idx & 255) * 2;
                    *(unsigned*)&S_lds[r * 536 + c] = (unsigned)v[ii];
                }
            }
            bar_lgkm();

            if (w < 6) {
                const int mt = w & 1, ct = w >> 1;
                const int arow = mt * 16 + (lane & 15);
                f32x4 ae = {0.f, 0.f, 0.f, 0.f}, ao = {0.f, 0.f, 0.f, 0.f};
                const s16x8* wl = (const s16x8*)W_lds;
#pragma unroll
                for (int kt = 0; kt < 16; kt += 2) {
                    s16x8 a0 = *(const s16x8*)&S_lds[arow * 536 + kt * 32 + kbase];
                    s16x8 a1 = *(const s16x8*)&S_lds[arow * 536 + (kt + 1) * 32 + kbase];
                    ae = __builtin_amdgcn_mfma_f32_16x16x32_bf16(a0, wl[(ct * 16 + kt) * 64 + lane], ae, 0, 0, 0);
                    ao = __builtin_amdgcn_mfma_f32_16x16x32_bf16(a1, wl[(ct * 16 + kt + 1) * 64 + lane], ao, 0, 0, 0);
                }
                f32x4 a4 = ae + ao;
                const int cout = b * 48 + ct * 16 + (lane & 15);
                const int rbase = mt * 16 + (lane >> 4) * 4;
#pragma unroll
                for (int r = 0; r < 4; ++r)
                    st_pt(&Upl[(size_t)(rbase + r) * 1536 + cout], __float_as_uint(a4[r]), want);
            }

            float guv = 0.f, suv = 0.f;
            if (tid < 512) {
                unsigned long long u0, u1, u2;
                const unsigned long long* q0 = &Upl[b * 1536 + tid];
                const unsigned long long* q1 = &Upl[b * 1536 + 512 + tid];
                const unsigned long long* q2 = &Upl[b * 1536 + 1024 + tid];
                ld3_pt(q0, q1, q2, u0, u1, u2);
                while (((unsigned)(u0 >> 32) != want) | ((unsigned)(u1 >> 32) != want) |
                       ((unsigned)(u2 >> 32) != want)) {
                    __builtin_amdgcn_s_sleep(1);
                    ld3_pt(q0, q1, q2, u0, u1, u2);
                }
                float qv = __uint_as_float((unsigned)u0);
                guv = __uint_as_float((unsigned)u1);
                suv = __uint_as_float((unsigned)u2);
                tq[tid] = tanhf(qv + bprev_h);
            }
            bar_lgkm();

            {
                float tqv[8];
                const f32x4* tp = (const f32x4*)&tq[lane * 8];
                f32x4 t0 = tp[0], t1 = tp[1];
#pragma unroll
                for (int j = 0; j < 4; ++j) { tqv[j] = t0[j]; tqv[4 + j] = t1[j]; }
#pragma unroll
                for (int s8 = 0; s8 < 8; ++s8) {
                    int s = w * 8 + s8;
                    s16x8 tv = *(const s16x8*)&Ta_bf[((size_t)(b * 128 + s)) * 512 + lane * 8];
                    float a = 0.f;
#pragma unroll
                    for (int j = 0; j < 8; ++j) {
                        float ta = bf2f(tv[j]);
                        float num = ta + tqv[j];
                        float den = fmaf(ta, tqv[j], 1.0f);
                        a = fmaf(wv[j], num * __builtin_amdgcn_rcpf(den), a);
                    }
#pragma unroll
                    for (int off = 32; off; off >>= 1) a += __shfl_xor(a, off, 64);
                    if (lane == 0) sc[s] = a;
                }
            }
            bar_lgkm();
            if (w == 0) {
                float v0 = sc[lane], v1 = sc[lane + 64];
                float m = fmaxf(v0, v1);
#pragma unroll
                for (int off = 32; off; off >>= 1) m = fmaxf(m, __shfl_xor(m, off, 64));
                float p0 = __expf(v0 - m), p1 = __expf(v1 - m);
                float sm = p0 + p1;
#pragma unroll
                for (int off = 32; off; off >>= 1) sm += __shfl_xor(sm, off, 64);
                float inv = __builtin_amdgcn_rcpf(sm);
                al[lane] = p0 * inv; al[lane + 64] = p1 * inv;
            }
            bar_lgkm();
            {
                float a0 = 0.f, a1 = 0.f;
#pragma unroll
                for (int q = 0; q < 16; ++q) {
                    s16x8 v = Mp[q];
#pragma unroll
                    for (int j = 0; j < 8; j += 2) {
                        a0 = fmaf(al[q * 8 + j],     bf2f(v[j]),     a0);
                        a1 = fmaf(al[q * 8 + j + 1], bf2f(v[j + 1]), a1);
                    }
                }
                if (mat) cs[hh] = a0 + a1; else cg[hh] = a0 + a1;
            }
            bar_lgkm();
            if (tid < 512) {
                int h = tid;
                float g  = guv + xg_pre + cg[h];
                float r  = __builtin_amdgcn_rcpf(1.0f + __expf(-g));
                float sp = suv + xs_pre + cs[h];
                float e  = __expf(2.0f * sp);
                float st = 1.0f - 2.0f * __builtin_amdgcn_rcpf(e + 1.0f);
                float ns = s_reg + r * (st - s_reg);
                s_reg = ns;
                float dv = ns + senth;
                float dvn = __shfl_down(dv, 1, 64);
                if (!(lane & 1)) {
                    unsigned pk = (unsigned)f2bf(dv) | ((unsigned)f2bf(dvn) << 16);
                    st_coh32((unsigned*)dh + ((((size_t)t * 32 + b) * 512 + h) >> 1), pk);
                }
                if (t < 63) {
                    float nsn = __shfl_down(ns, 1, 64);
                    if (!(lane & 1)) {
                        unsigned pay = (unsigned)f2bf(ns) | ((unsigned)f2bf(nsn) << 16);
                        st_pt(&Spl[b * 256 + (h >> 1)], pay, (unsigned)(t + 2));
                    }
                }
            }
            if ((t & 7) == 7) asm volatile("s_waitcnt vmcnt(0)" ::: "memory");
            bar_lgkm();
            if ((t & 7) == 7 && tid == 0)
                st_coh32(&prog[b * 16], (unsigned)(t + 1));
        }
    } else {
        // =================== CONSUMER ROLE ===================
        const int k4 = blockIdx.x - NB;                        // 0..223
        unsigned short* As = (unsigned short*)smem;            // [256][136]

        // ---- (a) cooperative W_out pre-pack into MFMA B fragments ----
        for (int u = k4 * 16 + w; u < 32000; u += 224 * 16) {
            int ct = u >> 4, kt = u & 15;
            int c = ct * 16 + (lane & 15);
            int kb = kt * 32 + (lane >> 4) * 8;
            s16x8 v;
#pragma unroll
            for (int j = 0; j < 8; ++j)
                v[j] = (short)f2bf(W_out[(size_t)(kb + j) * 32000 + c]);
            union { s16x8 s; u32x4 u4; } cv; cv.s = v;
            st_coh_x4(&wpk[(size_t)u * 512 + (size_t)lane * 8], cv.u4);
        }
        asm volatile("s_waitcnt vmcnt(0)" ::: "memory");
        __syncthreads();
        if (tid == 0)
            __hip_atomic_fetch_add(packdone, 1u, __ATOMIC_RELAXED, __HIP_MEMORY_SCOPE_AGENT);
        if (w == 0 && lane == 0) {
            while (__hip_atomic_load(packdone, __ATOMIC_RELAXED, __HIP_MEMORY_SCOPE_AGENT) < 224u)
                __builtin_amdgcn_s_sleep(16);
        }
        __syncthreads();
        __builtin_amdgcn_fence(__ATOMIC_ACQUIRE, "agent");   // ONE L2 invalidate
        __syncthreads();

        // ---- (b) persistent OUT GEMM (R16 interleaved tile order) ----
        const int wr = w >> 2, wc = w & 3;
        const int k0f = (lane >> 4) * 8;
        const int rsel = lane & 15;
        const int rg = (lane >> 4) * 4;
        const int ar4 = tid >> 2, aq = tid & 3;
        const s16x8* wpk8 = (const s16x8*)wpk;

        for (int idx = k4; idx < 1000; idx += 224) {
            const int tm = idx / 125, tn = idx - tm * 125;
            const unsigned need = (unsigned)(tm * 8 + 8);
            if (w == 0) {
                for (;;) {
                    unsigned v = 0xFFFFFFFFu;
                    if (lane < 32) v = ld_coh32(&prog[lane * 16]);
                    if (__all(v >= need)) break;
                    __builtin_amdgcn_s_sleep(64);
                }
            }
            __syncthreads();

            const int m0 = tm * 256, n0 = tn * 256;
            f32x4 acc[4][4];
#pragma unroll
            for (int i = 0; i < 4; ++i)
#pragma unroll
                for (int j = 0; j < 4; ++j) { f32x4 z = {0.f, 0.f, 0.f, 0.f}; acc[i][j] = z; }

#pragma unroll
            for (int kq = 0; kq < 4; ++kq) {
                __syncthreads();
                {   // stage 4 k-tiles of A: 64B contiguous coherent per thread
                    const unsigned short* sp = &dh[(size_t)(m0 + ar4) * 512 + kq * 128 + aq * 32];
                    u32x4 a0, a1, a2, a3;
                    ld64_coh(sp, a0, a1, a2, a3);
                    int base = ar4 * 136 + aq * 32;
                    *(u32x4*)&As[base]      = a0;
                    *(u32x4*)&As[base + 8]  = a1;
                    *(u32x4*)&As[base + 16] = a2;
                    *(u32x4*)&As[base + 24] = a3;
                }
                __syncthreads();
#pragma unroll
                for (int kk = 0; kk < 4; ++kk) {
                    const int kt = kq * 4 + kk;
                    s16x8 bfr[4], af[4];
#pragma unroll
                    for (int j = 0; j < 4; ++j)
                        bfr[j] = wpk8[(size_t)(((tn * 16 + wc * 4 + j) * 16 + kt)) * 64 + lane];
#pragma unroll
                    for (int i = 0; i < 4; ++i)
                        af[i] = *(const s16x8*)&As[(wr * 64 + i * 16 + rsel) * 136 + kk * 32 + k0f];
#pragma unroll
                    for (int i = 0; i < 4; ++i)
#pragma unroll
                        for (int j = 0; j < 4; ++j)
                            acc[i][j] = __builtin_amdgcn_mfma_f32_16x16x32_bf16(af[i], bfr[j], acc[i][j], 0, 0, 0);
                }
            }

            // epilogue: trow = t*32 + b -> out[(b*64+t)][col]
#pragma unroll
            for (int i = 0; i < 4; ++i)
#pragma unroll
                for (int j = 0; j < 4; ++j) {
                    int trow0 = m0 + wr * 64 + i * 16 + rg;
                    int col   = n0 + wc * 64 + j * 16 + rsel;
                    float bb_ = 1.5f * b_out[col];
#pragma unroll
                    for (int r = 0; r < 4; ++r) {
                        int trow = trow0 + r;
                        int bb = trow & 31, tt = trow >> 5;
                        out[(size_t)(bb * 64 + tt) * 32000 + col] = acc[i][j][r] + bb_;
                    }
                }
        }
    }
}

// ---------------------------------------------------------------------------
extern "C" void kernel_launch(void* const* d_in, const int* in_sizes, int n_in,
                              void* d_out, int out_size, void* d_ws, size_t ws_size,
                              hipStream_t stream) {
    const float* content  = (const float*)d_in[0];
    const float* sentiment= (const float*)d_in[1];
    const float* hiddens  = (const float*)d_in[2];
    const int*   target   = (const int*)  d_in[3];
    const float* embed    = (const float*)d_in[4];
    const float* W_enc = (const float*)d_in[5];  const float* b_enc = (const float*)d_in[6];
    const float* W_prev= (const float*)d_in[7];  const float* b_prev= (const float*)d_in[8];
    const float* W_att = (const float*)d_in[9];  /* b_att (d_in[10]) cancels in softmax */
    const float* Wi_g  = (const float*)d_in[11]; const float* bi_g  = (const float*)d_in[12];
    const float* Wh_g  = (const float*)d_in[13]; const float* bh_g  = (const float*)d_in[14];
    const float* Wc_g  = (const float*)d_in[15]; const float* bc_g  = (const float*)d_in[16];
    const float* Wi    = (const float*)d_in[17]; const float* bi    = (const float*)d_in[18];
    const float* Wh    = (const float*)d_in[19]; const float* bh    = (const float*)d_in[20];
    const float* Wc    = (const float*)d_in[21]; const float* bc    = (const float*)d_in[22];
    const float* W_out = (const float*)d_in[23]; const float* b_out = (const float*)d_in[24];
    float* out = (float*)d_out;

    // workspace layout (bytes)
    char* ws = (char*)d_ws;
    unsigned short* wfrag = (unsigned short*)ws;                       // 1.5 MB @0
    unsigned long long* Spl = (unsigned long long*)(ws + 0x180000);    // 64 KB  (pay,tag)
    unsigned long long* Upl = (unsigned long long*)(ws + 0x190000);    // 384 KB (pay,tag)
    unsigned* prog = (unsigned*)(ws + 0x1F0000);                       // 2 KB progress flags
    unsigned* packdone = (unsigned*)(ws + 0x1F0800);                   // 4 B
    unsigned short* Ta_bf   = (unsigned short*)(ws + 0x200000);        // 4 MB [4096][512]
    unsigned short* hWcg_t  = (unsigned short*)(ws + 0x600000);        // 4 MB [32][512][128]
    unsigned short* hWc_t   = (unsigned short*)(ws + 0xA00000);        // 4 MB
    float* xgxs     = (float*)(ws + 0xE00000);                         // 8 MB [2048][1024]
    unsigned short* dh      = (unsigned short*)(ws + 0x1600000);       // 2 MB t-major [64*32][512]
    unsigned short* wpk     = (unsigned short*)(ws + 0x1800000);       // 32.75 MB packed W_out

    // zero tag planes + progress flags + packdone every launch
    hipMemsetAsync(ws + 0x180000, 0, 0x71000, stream);

    // K0+K1+K2 fused pre-kernel
    pre_kernel<<<896, 256, 0, stream>>>(
        hiddens, W_enc, Wc_g, Wc, b_enc, Ta_bf, hWcg_t, hWc_t,
        embed, target, Wi_g, Wi, bi_g, bh_g, bc_g, bi, bh, bc, xgxs,
        W_prev, Wh_g, Wh, wfrag);

    // K3+K4 fused: scan (blocks 0-31) + pack + tag-gated OUT gemm (32-255)
    fused_scan_out<<<256, 1024, 0, stream>>>(
        content, sentiment, b_prev, W_att, Ta_bf, hWcg_t, hWc_t,
        xgxs, wfrag, Spl, Upl, dh, prog, packdone, wpk, W_out, b_out, out);

    (void)in_sizes; (void)n_in; (void)out_size; (void)ws_size;
}

// Round 19
// 1250.588 us; speedup vs baseline: 1.0999x; 1.0074x over previous
//
#include <hip/hip_runtime.h>
#include <hip/hip_bf16.h>
#include <math.h>

// Problem dims
#define NB 32
#define NS 128
#define NT 64
#define NV 32000
#define NE 256
#define NH 512

typedef short s16x8 __attribute__((ext_vector_type(8)));
typedef float f32x4 __attribute__((ext_vector_type(4)));
typedef unsigned u32x4 __attribute__((ext_vector_type(4)));

__device__ __forceinline__ unsigned short f2bf(float x) {
    union { float f; unsigned u; } v; v.f = x;
    unsigned r = v.u + 0x7FFFu + ((v.u >> 16) & 1u);   // RNE
    return (unsigned short)(r >> 16);
}
__device__ __forceinline__ float bf2f(short h) {
    union { unsigned u; float f; } x;
    x.u = ((unsigned)(unsigned short)h) << 16;
    return x.f;
}

// lgkm-only block barrier: drains LDS ops but leaves global ops in flight.
__device__ __forceinline__ void bar_lgkm() {
    asm volatile("s_waitcnt lgkmcnt(0)" ::: "memory");
    __builtin_amdgcn_sched_barrier(0);
    __builtin_amdgcn_s_barrier();
    __builtin_amdgcn_sched_barrier(0);
}

// ---- coherent (LLC-point) ops ----
__device__ __forceinline__ void st_pt(unsigned long long* p, unsigned pay, unsigned tag) {
    unsigned long long v = (unsigned long long)pay | ((unsigned long long)tag << 32);
    asm volatile("global_store_dwordx2 %0, %1, off sc0 sc1" :: "v"(p), "v"(v) : "memory");
}
__device__ __forceinline__ void st_coh32(unsigned* p, unsigned v) {
    asm volatile("global_store_dword %0, %1, off sc0 sc1" :: "v"(p), "v"(v) : "memory");
}
__device__ __forceinline__ unsigned ld_coh32(const unsigned* p) {
    unsigned v;
    asm volatile("global_load_dword %0, %1, off sc0 sc1\n\ts_waitcnt vmcnt(0)"
                 : "=v"(v) : "v"(p) : "memory");
    return v;
}
__device__ __forceinline__ void st_coh_x4(void* p, u32x4 v) {
    asm volatile("global_store_dwordx4 %0, %1, off sc0 sc1" :: "v"(p), "v"(v) : "memory");
}
// 64B contiguous coherent load (4 x 16B, one drain)
__device__ __forceinline__ void ld64_coh(const void* p, u32x4& a, u32x4& b, u32x4& c, u32x4& d) {
    asm volatile(
        "global_load_dwordx4 %0, %4, off sc0 sc1\n\t"
        "global_load_dwordx4 %1, %4, off offset:16 sc0 sc1\n\t"
        "global_load_dwordx4 %2, %4, off offset:32 sc0 sc1\n\t"
        "global_load_dwordx4 %3, %4, off offset:48 sc0 sc1\n\t"
        "s_waitcnt vmcnt(0)"
        : "=&v"(a), "=&v"(b), "=&v"(c), "=&v"(d)
        : "v"(p) : "memory");
}
// ---- non-temporal (evict-first, no L2 pollution) consumer stream ops ----
__device__ __forceinline__ void ld4_nt(const void* p0, const void* p1,
                                       const void* p2, const void* p3,
                                       u32x4& a, u32x4& b, u32x4& c, u32x4& d) {
    asm volatile(
        "global_load_dwordx4 %0, %4, off nt\n\t"
        "global_load_dwordx4 %1, %5, off nt\n\t"
        "global_load_dwordx4 %2, %6, off nt\n\t"
        "global_load_dwordx4 %3, %7, off nt\n\t"
        "s_waitcnt vmcnt(0)"
        : "=&v"(a), "=&v"(b), "=&v"(c), "=&v"(d)
        : "v"(p0), "v"(p1), "v"(p2), "v"(p3)
        : "memory");
}
__device__ __forceinline__ void st_nt32(float* p, float v) {
    asm volatile("global_store_dword %0, %1, off nt" :: "v"(p), "v"(v) : "memory");
}
__device__ __forceinline__ void ld8_pt(const unsigned long long* b0, unsigned long long* v) {
    unsigned long long v0, v1, v2, v3, v4, v5, v6, v7;
    asm volatile(
        "global_load_dwordx2 %0, %8, off sc0 sc1\n\t"
        "global_load_dwordx2 %1, %9, off sc0 sc1\n\t"
        "global_load_dwordx2 %2, %10, off sc0 sc1\n\t"
        "global_load_dwordx2 %3, %11, off sc0 sc1\n\t"
        "global_load_dwordx2 %4, %12, off sc0 sc1\n\t"
        "global_load_dwordx2 %5, %13, off sc0 sc1\n\t"
        "global_load_dwordx2 %6, %14, off sc0 sc1\n\t"
        "global_load_dwordx2 %7, %15, off sc0 sc1\n\t"
        "s_waitcnt vmcnt(0)"
        : "=&v"(v0), "=&v"(v1), "=&v"(v2), "=&v"(v3),
          "=&v"(v4), "=&v"(v5), "=&v"(v6), "=&v"(v7)
        : "v"(b0), "v"(b0 + 1024), "v"(b0 + 2048), "v"(b0 + 3072),
          "v"(b0 + 4096), "v"(b0 + 5120), "v"(b0 + 6144), "v"(b0 + 7168)
        : "memory");
    v[0] = v0; v[1] = v1; v[2] = v2; v[3] = v3;
    v[4] = v4; v[5] = v5; v[6] = v6; v[7] = v7;
}
__device__ __forceinline__ void ld3_pt(const unsigned long long* p0,
                                       const unsigned long long* p1,
                                       const unsigned long long* p2,
                                       unsigned long long& a, unsigned long long& b,
                                       unsigned long long& c) {
    asm volatile(
        "global_load_dwordx2 %0, %3, off sc0 sc1\n\t"
        "global_load_dwordx2 %1, %4, off sc0 sc1\n\t"
        "global_load_dwordx2 %2, %5, off sc0 sc1\n\t"
        "s_waitcnt vmcnt(0)"
        : "=&v"(a), "=&v"(b), "=&v"(c)
        : "v"(p0), "v"(p1), "v"(p2)
        : "memory");
}

// ---------------------------------------------------------------------------
// Shared MFMA GEMM body (128x128 tile, BK=32, 4 waves). MODE 0 (PRE), 1 (XP).
// ---------------------------------------------------------------------------
template<int MODE>
__device__ __forceinline__ void gemm_body(
    int bidx, unsigned short* As, unsigned short* Bs,
    const float* __restrict__ Af, const int* __restrict__ gidx,
    const float* __restrict__ B0, const float* __restrict__ B1, const float* __restrict__ B2,
    const float* __restrict__ e0, const float* __restrict__ e1, const float* __restrict__ e2,
    const float* __restrict__ e3, const float* __restrict__ e4, const float* __restrict__ e5,
    void* __restrict__ O0v, void* __restrict__ O1v, void* __restrict__ O2v)
{
    constexpr int M   = (MODE == 0) ? 4096 : 2048;
    constexpr int K   = (MODE == 0) ? 1024 : 256;
    constexpr int LDA = (MODE == 0) ? 1024 : 256;
    constexpr int MB  = M / 128;

    const int bm = bidx % MB, bn = bidx / MB;
    const int m0 = bm * 128, n0 = bn * 128;

    const float* Bp; int ldb, coff;
    if constexpr (MODE == 0) {
        int sub = n0 >> 9;
        Bp   = (sub == 0) ? B0 : (sub == 1) ? B1 : B2;
        ldb  = (sub == 1) ? 1024 : 512;
        coff = n0 & 511;
    } else {
        if (n0 < 512) { Bp = B0; ldb = 1024; coff = n0; }
        else          { Bp = B1; ldb = 512;  coff = n0 - 512; }
    }

    const int tid = threadIdx.x, lane = tid & 63, w = tid >> 6;
    const int wr = w >> 1, wc = w & 1;
    const int k0f = (lane >> 4) * 8;
    const int rsel = lane & 15;

    f32x4 acc[4][4];
#pragma unroll
    for (int i = 0; i < 4; ++i)
#pragma unroll
        for (int j = 0; j < 4; ++j) { f32x4 z = {0.f, 0.f, 0.f, 0.f}; acc[i][j] = z; }

    for (int kt = 0; kt < K / 32; ++kt) {
        const int k0 = kt * 32;
        __syncthreads();
#pragma unroll
        for (int i = 0; i < 16; ++i) {
            int idx = tid + i * 256;
            int r = idx >> 5, k = idx & 31;
            unsigned short v;
            if constexpr (MODE == 1) {
                int g = gidx[m0 + r];
                v = f2bf(Af[(size_t)g * 256 + k0 + k]);
            } else {
                v = f2bf(Af[(size_t)(m0 + r) * LDA + k0 + k]);
            }
            As[r * 40 + k] = v;
        }
#pragma unroll
        for (int i = 0; i < 16; ++i) {
            int idx = tid + i * 256;
            int k = idx >> 7, c = idx & 127;
            Bs[c * 40 + k] = f2bf(Bp[(size_t)(k0 + k) * ldb + coff + c]);
        }
        __syncthreads();

        s16x8 af[4], bf[4];
#pragma unroll
        for (int i = 0; i < 4; ++i)
            af[i] = *(const s16x8*)&As[(wr * 64 + i * 16 + rsel) * 40 + k0f];
#pragma unroll
        for (int j = 0; j < 4; ++j)
            bf[j] = *(const s16x8*)&Bs[(wc * 64 + j * 16 + rsel) * 40 + k0f];
#pragma unroll
        for (int i = 0; i < 4; ++i)
#pragma unroll
            for (int j = 0; j < 4; ++j)
                acc[i][j] = __builtin_amdgcn_mfma_f32_16x16x32_bf16(af[i], bf[j], acc[i][j], 0, 0, 0);
    }

    const int rg = (lane >> 4) * 4;
#pragma unroll
    for (int i = 0; i < 4; ++i)
#pragma unroll
        for (int j = 0; j < 4; ++j) {
            int row0 = m0 + wr * 64 + i * 16 + rg;
            int col  = n0 + wc * 64 + j * 16 + rsel;
            if constexpr (MODE == 0) {
                int sub = col >> 9;
                if (sub == 0) {
                    unsigned short* Ta = (unsigned short*)O0v;
#pragma unroll
                    for (int r = 0; r < 4; ++r)
                        Ta[(size_t)(row0 + r) * 512 + col] = f2bf(tanhf(acc[i][j][r] + e0[col]));
                } else {
                    int h = col & 511;
                    int bb = row0 >> 7, s0 = row0 & 127;
                    unsigned long long pk = 0;
#pragma unroll
                    for (int r = 0; r < 4; ++r)
                        pk |= (unsigned long long)f2bf(acc[i][j][r]) << (16 * r);
                    unsigned short* dstp = (sub == 1) ? (unsigned short*)O1v : (unsigned short*)O2v;
                    *(unsigned long long*)&dstp[(size_t)((bb * 512 + h) * 128 + s0)] = pk;
                }
            } else {
                float* Of = (float*)O0v;
                float bias;
                if (col < 512) bias = e0[col] + e1[col] + e2[col];
                else { int h = col - 512; bias = e3[h] + e4[h] + e5[h]; }
#pragma unroll
                for (int r = 0; r < 4; ++r)
                    Of[(size_t)(row0 + r) * 1024 + col] = acc[i][j][r] + bias;
            }
        }
}

// ---------------------------------------------------------------------------
// Pre-kernel: K1 (384 blocks) + K2 (128 blocks) + K0 (384 blocks, 4 units ea)
// ---------------------------------------------------------------------------
__global__ __launch_bounds__(256, 2) void pre_kernel(
    const float* __restrict__ hiddens,
    const float* __restrict__ W_enc, const float* __restrict__ Wc_g, const float* __restrict__ Wc,
    const float* __restrict__ b_enc,
    unsigned short* __restrict__ Ta_bf, unsigned short* __restrict__ hWcg_t,
    unsigned short* __restrict__ hWc_t,
    const float* __restrict__ embed, const int* __restrict__ target,
    const float* __restrict__ Wi_g, const float* __restrict__ Wi,
    const float* __restrict__ bi_g, const float* __restrict__ bh_g, const float* __restrict__ bc_g,
    const float* __restrict__ bi, const float* __restrict__ bh, const float* __restrict__ bc,
    float* __restrict__ xgxs,
    const float* __restrict__ Wp, const float* __restrict__ Whg, const float* __restrict__ Wh,
    unsigned short* __restrict__ wfrag)
{
    __shared__ unsigned short As[128 * 40];
    __shared__ unsigned short Bs[128 * 40];
    const int bid = blockIdx.x;

    if (bid < 384) {
        gemm_body<0>(bid, As, Bs, hiddens, nullptr, W_enc, Wc_g, Wc,
                     b_enc, nullptr, nullptr, nullptr, nullptr, nullptr,
                     (void*)Ta_bf, (void*)hWcg_t, (void*)hWc_t);
    } else if (bid < 512) {
        gemm_body<1>(bid - 384, As, Bs, embed, target, Wi_g, Wi, nullptr,
                     bi_g, bh_g, bc_g, bi, bh, bc,
                     (void*)xgxs, nullptr, nullptr);
    } else {
        const int lane = threadIdx.x & 63;
        const int unit = (bid - 512) * 4 + (threadIdx.x >> 6);
        int ct = unit >> 4, kt = unit & 15;
        int c = ct * 16 + (lane & 15);
        int kb = kt * 32 + (lane >> 4) * 8;
        s16x8 v;
#pragma unroll
        for (int j = 0; j < 8; ++j) {
            int k = kb + j;
            float x;
            if (c < 512)       x = Wp[k * 512 + c];
            else if (c < 1024) x = Whg[k * 1024 + (c - 512)];
            else               x = Wh[k * 512 + (c - 1024)];
            v[j] = (short)f2bf(x);
        }
        ((s16x8*)wfrag)[unit * 64 + lane] = v;
    }
}

// ---------------------------------------------------------------------------
// Fused K3+K4: 256 blocks x 1024 threads. R18 structure; consumer streams
// now NON-TEMPORAL (wpk loads + out stores) so they stop evicting the scan
// blocks' L2-resident working sets (Ta/hW/W).
// ---------------------------------------------------------------------------
__global__ __launch_bounds__(1024) void fused_scan_out(
    const float* __restrict__ content, const float* __restrict__ sentiment,
    const float* __restrict__ b_prev,  const float* __restrict__ W_att,
    const unsigned short* __restrict__ Ta_bf,
    const unsigned short* __restrict__ hWcg_t,
    const unsigned short* __restrict__ hWc_t,
    const float* __restrict__ xgxs, const unsigned short* __restrict__ wfrag,
    unsigned long long* __restrict__ Spl, unsigned long long* __restrict__ Upl,
    unsigned short* __restrict__ dh, unsigned* __restrict__ prog,
    unsigned* __restrict__ packdone, unsigned short* __restrict__ wpk,
    const float* __restrict__ W_out, const float* __restrict__ b_out,
    float* __restrict__ out)
{
    __shared__ __attribute__((aligned(16))) char smem[90624];
    const int tid = threadIdx.x, lane = tid & 63, w = tid >> 6;

    if (blockIdx.x < NB) {
        // =================== SCAN ROLE (R18 verbatim) ===================
        const int b = blockIdx.x;
        unsigned short* W_lds = (unsigned short*)smem;               // 48 KB
        unsigned short* S_lds = (unsigned short*)(smem + 49152);     // 33.5 KB
        float* tq = (float*)(smem + 83456);
        float* sc = (float*)(smem + 85504);
        float* al = (float*)(smem + 86016);
        float* cg = (float*)(smem + 86528);
        float* cs = (float*)(smem + 88576);

        {
            const s16x8* src = (const s16x8*)wfrag + (size_t)b * (3 * 16 * 64);
            s16x8* dst = (s16x8*)W_lds;
            for (int i = tid; i < 3 * 16 * 64; i += 1024) dst[i] = src[i];
        }
        float s_reg = 0.f, senth = 0.f, bprev_h = 0.f;
        if (tid < 512) {
            s_reg   = content[b * 512 + tid];
            senth   = 0.5f * sentiment[b * 512 + tid];
            bprev_h = b_prev[tid];
        }
        float wv[8];
        {
            const f32x4* wa = (const f32x4*)&W_att[lane * 8];
            f32x4 a0 = wa[0], a1 = wa[1];
#pragma unroll
            for (int j = 0; j < 4; ++j) { wv[j] = a0[j]; wv[4 + j] = a1[j]; }
        }
        const int kbase = (lane >> 4) * 8;
        const int mat = tid >> 9, hh = tid & 511;
        const s16x8* Mp = (const s16x8*)((mat ? hWc_t : hWcg_t) + ((size_t)(b * 512 + hh)) * 128);

        if (tid < 512) {
            float nsn = __shfl_down(s_reg, 1, 64);
            if (!(lane & 1)) {
                unsigned pay = (unsigned)f2bf(s_reg) | ((unsigned)f2bf(nsn) << 16);
                st_pt(&Spl[b * 256 + (tid >> 1)], pay, 1u);
            }
        }

        for (int t = 0; t < 64; ++t) {
            const unsigned want = (unsigned)(t + 1);
            float xg_pre = 0.f, xs_pre = 0.f;
            if (tid < 512) {
                xg_pre = xgxs[((size_t)b * 64 + t) * 1024 + tid];
                xs_pre = xgxs[((size_t)b * 64 + t) * 1024 + 512 + tid];
            }

            // Phase A: poll-stage all-batch S(t) into LDS
            {
                unsigned long long v[8];
                const unsigned long long* base = &Spl[tid];
                ld8_pt(base, v);
                for (;;) {
                    bool ok = true;
#pragma unroll
                    for (int ii = 0; ii < 8; ++ii) ok &= ((unsigned)(v[ii] >> 32) == want);
                    if (ok) break;
                    __builtin_amdgcn_s_sleep(1);
                    ld8_pt(base, v);
                }
#pragma unroll
                for (int ii = 0; ii < 8; ++ii) {
                    int idx = tid + ii * 1024;
                    int r = idx >> 8, c = (idx & 255) * 2;
                    *(unsigned*)&S_lds[r * 536 + c] = (unsigned)v[ii];
                }
            }
            bar_lgkm();

            if (w < 6) {
                const int mt = w & 1, ct = w >> 1;
                const int arow = mt * 16 + (lane & 15);
                f32x4 ae = {0.f, 0.f, 0.f, 0.f}, ao = {0.f, 0.f, 0.f, 0.f};
                const s16x8* wl = (const s16x8*)W_lds;
#pragma unroll
                for (int kt = 0; kt < 16; kt += 2) {
                    s16x8 a0 = *(const s16x8*)&S_lds[arow * 536 + kt * 32 + kbase];
                    s16x8 a1 = *(const s16x8*)&S_lds[arow * 536 + (kt + 1) * 32 + kbase];
                    ae = __builtin_amdgcn_mfma_f32_16x16x32_bf16(a0, wl[(ct * 16 + kt) * 64 + lane], ae, 0, 0, 0);
                    ao = __builtin_amdgcn_mfma_f32_16x16x32_bf16(a1, wl[(ct * 16 + kt + 1) * 64 + lane], ao, 0, 0, 0);
                }
                f32x4 a4 = ae + ao;
                const int cout = b * 48 + ct * 16 + (lane & 15);
                const int rbase = mt * 16 + (lane >> 4) * 4;
#pragma unroll
                for (int r = 0; r < 4; ++r)
                    st_pt(&Upl[(size_t)(rbase + r) * 1536 + cout], __float_as_uint(a4[r]), want);
            }

            float guv = 0.f, suv = 0.f;
            if (tid < 512) {
                unsigned long long u0, u1, u2;
                const unsigned long long* q0 = &Upl[b * 1536 + tid];
                const unsigned long long* q1 = &Upl[b * 1536 + 512 + tid];
                const unsigned long long* q2 = &Upl[b * 1536 + 1024 + tid];
                ld3_pt(q0, q1, q2, u0, u1, u2);
                while (((unsigned)(u0 >> 32) != want) | ((unsigned)(u1 >> 32) != want) |
                       ((unsigned)(u2 >> 32) != want)) {
                    __builtin_amdgcn_s_sleep(1);
                    ld3_pt(q0, q1, q2, u0, u1, u2);
                }
                float qv = __uint_as_float((unsigned)u0);
                guv = __uint_as_float((unsigned)u1);
                suv = __uint_as_float((unsigned)u2);
                tq[tid] = tanhf(qv + bprev_h);
            }
            bar_lgkm();

            {
                float tqv[8];
                const f32x4* tp = (const f32x4*)&tq[lane * 8];
                f32x4 t0 = tp[0], t1 = tp[1];
#pragma unroll
                for (int j = 0; j < 4; ++j) { tqv[j] = t0[j]; tqv[4 + j] = t1[j]; }
#pragma unroll
                for (int s8 = 0; s8 < 8; ++s8) {
                    int s = w * 8 + s8;
                    s16x8 tv = *(const s16x8*)&Ta_bf[((size_t)(b * 128 + s)) * 512 + lane * 8];
                    float a = 0.f;
#pragma unroll
                    for (int j = 0; j < 8; ++j) {
                        float ta = bf2f(tv[j]);
                        float num = ta + tqv[j];
                        float den = fmaf(ta, tqv[j], 1.0f);
                        a = fmaf(wv[j], num * __builtin_amdgcn_rcpf(den), a);
                    }
#pragma unroll
                    for (int off = 32; off; off >>= 1) a += __shfl_xor(a, off, 64);
                    if (lane == 0) sc[s] = a;
                }
            }
            bar_lgkm();
            if (w == 0) {
                float v0 = sc[lane], v1 = sc[lane + 64];
                float m = fmaxf(v0, v1);
#pragma unroll
                for (int off = 32; off; off >>= 1) m = fmaxf(m, __shfl_xor(m, off, 64));
                float p0 = __expf(v0 - m), p1 = __expf(v1 - m);
                float sm = p0 + p1;
#pragma unroll
                for (int off = 32; off; off >>= 1) sm += __shfl_xor(sm, off, 64);
                float inv = __builtin_amdgcn_rcpf(sm);
                al[lane] = p0 * inv; al[lane + 64] = p1 * inv;
            }
            bar_lgkm();
            {
                float a0 = 0.f, a1 = 0.f;
#pragma unroll
                for (int q = 0; q < 16; ++q) {
                    s16x8 v = Mp[q];
#pragma unroll
                    for (int j = 0; j < 8; j += 2) {
                        a0 = fmaf(al[q * 8 + j],     bf2f(v[j]),     a0);
                        a1 = fmaf(al[q * 8 + j + 1], bf2f(v[j + 1]), a1);
                    }
                }
                if (mat) cs[hh] = a0 + a1; else cg[hh] = a0 + a1;
            }
            bar_lgkm();
            if (tid < 512) {
                int h = tid;
                float g  = guv + xg_pre + cg[h];
                float r  = __builtin_amdgcn_rcpf(1.0f + __expf(-g));
                float sp = suv + xs_pre + cs[h];
                float e  = __expf(2.0f * sp);
                float st = 1.0f - 2.0f * __builtin_amdgcn_rcpf(e + 1.0f);
                float ns = s_reg + r * (st - s_reg);
                s_reg = ns;
                float dv = ns + senth;
                float dvn = __shfl_down(dv, 1, 64);
                if (!(lane & 1)) {
                    unsigned pk = (unsigned)f2bf(dv) | ((unsigned)f2bf(dvn) << 16);
                    st_coh32((unsigned*)dh + ((((size_t)t * 32 + b) * 512 + h) >> 1), pk);
                }
                if (t < 63) {
                    float nsn = __shfl_down(ns, 1, 64);
                    if (!(lane & 1)) {
                        unsigned pay = (unsigned)f2bf(ns) | ((unsigned)f2bf(nsn) << 16);
                        st_pt(&Spl[b * 256 + (h >> 1)], pay, (unsigned)(t + 2));
                    }
                }
            }
            if ((t & 7) == 7) asm volatile("s_waitcnt vmcnt(0)" ::: "memory");
            bar_lgkm();
            if ((t & 7) == 7 && tid == 0)
                st_coh32(&prog[b * 16], (unsigned)(t + 1));
        }
    } else {
        // =================== CONSUMER ROLE ===================
        const int k4 = blockIdx.x - NB;                        // 0..223
        unsigned short* As = (unsigned short*)smem;            // [256][136]

        // ---- (a) cooperative W_out pre-pack into MFMA B fragments ----
        for (int u = k4 * 16 + w; u < 32000; u += 224 * 16) {
            int ct = u >> 4, kt = u & 15;
            int c = ct * 16 + (lane & 15);
            int kb = kt * 32 + (lane >> 4) * 8;
            s16x8 v;
#pragma unroll
            for (int j = 0; j < 8; ++j)
                v[j] = (short)f2bf(W_out[(size_t)(kb + j) * 32000 + c]);
            union { s16x8 s; u32x4 u4; } cv; cv.s = v;
            st_coh_x4(&wpk[(size_t)u * 512 + (size_t)lane * 8], cv.u4);
        }
        asm volatile("s_waitcnt vmcnt(0)" ::: "memory");
        __syncthreads();
        if (tid == 0)
            __hip_atomic_fetch_add(packdone, 1u, __ATOMIC_RELAXED, __HIP_MEMORY_SCOPE_AGENT);
        if (w == 0 && lane == 0) {
            while (__hip_atomic_load(packdone, __ATOMIC_RELAXED, __HIP_MEMORY_SCOPE_AGENT) < 224u)
                __builtin_amdgcn_s_sleep(16);
        }
        __syncthreads();
        __builtin_amdgcn_fence(__ATOMIC_ACQUIRE, "agent");   // ONE L2 invalidate
        __syncthreads();

        // ---- (b) persistent OUT GEMM (nt streams) ----
        const int wr = w >> 2, wc = w & 3;
        const int k0f = (lane >> 4) * 8;
        const int rsel = lane & 15;
        const int rg = (lane >> 4) * 4;
        const int ar4 = tid >> 2, aq = tid & 3;
        const s16x8* wpk8 = (const s16x8*)wpk;

        for (int idx = k4; idx < 1000; idx += 224) {
            const int tm = idx / 125, tn = idx - tm * 125;
            const unsigned need = (unsigned)(tm * 8 + 8);
            if (w == 0) {
                for (;;) {
                    unsigned v = 0xFFFFFFFFu;
                    if (lane < 32) v = ld_coh32(&prog[lane * 16]);
                    if (__all(v >= need)) break;
                    __builtin_amdgcn_s_sleep(64);
                }
            }
            __syncthreads();

            const int m0 = tm * 256, n0 = tn * 256;
            f32x4 acc[4][4];
#pragma unroll
            for (int i = 0; i < 4; ++i)
#pragma unroll
                for (int j = 0; j < 4; ++j) { f32x4 z = {0.f, 0.f, 0.f, 0.f}; acc[i][j] = z; }

#pragma unroll
            for (int kq = 0; kq < 4; ++kq) {
                __syncthreads();
                {   // stage 4 k-tiles of A: 64B contiguous coherent per thread
                    const unsigned short* sp = &dh[(size_t)(m0 + ar4) * 512 + kq * 128 + aq * 32];
                    u32x4 a0, a1, a2, a3;
                    ld64_coh(sp, a0, a1, a2, a3);
                    int base = ar4 * 136 + aq * 32;
                    *(u32x4*)&As[base]      = a0;
                    *(u32x4*)&As[base + 8]  = a1;
                    *(u32x4*)&As[base + 16] = a2;
                    *(u32x4*)&As[base + 24] = a3;
                }
                __syncthreads();
#pragma unroll
                for (int kk = 0; kk < 4; ++kk) {
                    const int kt = kq * 4 + kk;
                    const s16x8* bp = wpk8 + (size_t)(((tn * 16 + wc * 4) * 16 + kt)) * 64 + lane;
                    u32x4 r0, r1, r2, r3;
                    ld4_nt(bp, bp + 1024, bp + 2048, bp + 3072, r0, r1, r2, r3);
                    union { u32x4 u; s16x8 s; } c0, c1, c2, c3;
                    c0.u = r0; c1.u = r1; c2.u = r2; c3.u = r3;
                    s16x8 bfr[4] = {c0.s, c1.s, c2.s, c3.s};
                    s16x8 af[4];
#pragma unroll
                    for (int i = 0; i < 4; ++i)
                        af[i] = *(const s16x8*)&As[(wr * 64 + i * 16 + rsel) * 136 + kk * 32 + k0f];
#pragma unroll
                    for (int i = 0; i < 4; ++i)
#pragma unroll
                        for (int j = 0; j < 4; ++j)
                            acc[i][j] = __builtin_amdgcn_mfma_f32_16x16x32_bf16(af[i], bfr[j], acc[i][j], 0, 0, 0);
                }
            }

            // epilogue: trow = t*32 + b -> out[(b*64+t)][col] (nt stores)
#pragma unroll
            for (int i = 0; i < 4; ++i)
#pragma unroll
                for (int j = 0; j < 4; ++j) {
                    int trow0 = m0 + wr * 64 + i * 16 + rg;
                    int col   = n0 + wc * 64 + j * 16 + rsel;
                    float bb_ = 1.5f * b_out[col];
#pragma unroll
                    for (int r = 0; r < 4; ++r) {
                        int trow = trow0 + r;
                        int bb = trow & 31, tt = trow >> 5;
                        st_nt32(&out[(size_t)(bb * 64 + tt) * 32000 + col], acc[i][j][r] + bb_);
                    }
                }
        }
    }
}

// ---------------------------------------------------------------------------
extern "C" void kernel_launch(void* const* d_in, const int* in_sizes, int n_in,
                              void* d_out, int out_size, void* d_ws, size_t ws_size,
                              hipStream_t stream) {
    const float* content  = (const float*)d_in[0];
    const float* sentiment= (const float*)d_in[1];
    const float* hiddens  = (const float*)d_in[2];
    const int*   target   = (const int*)  d_in[3];
    const float* embed    = (const float*)d_in[4];
    const float* W_enc = (const float*)d_in[5];  const float* b_enc = (const float*)d_in[6];
    const float* W_prev= (const float*)d_in[7];  const float* b_prev= (const float*)d_in[8];
    const float* W_att = (const float*)d_in[9];  /* b_att (d_in[10]) cancels in softmax */
    const float* Wi_g  = (const float*)d_in[11]; const float* bi_g  = (const float*)d_in[12];
    const float* Wh_g  = (const float*)d_in[13]; const float* bh_g  = (const float*)d_in[14];
    const float* Wc_g  = (const float*)d_in[15]; const float* bc_g  = (const float*)d_in[16];
    const float* Wi    = (const float*)d_in[17]; const float* bi    = (const float*)d_in[18];
    const float* Wh    = (const float*)d_in[19]; const float* bh    = (const float*)d_in[20];
    const float* Wc    = (const float*)d_in[21]; const float* bc    = (const float*)d_in[22];
    const float* W_out = (const float*)d_in[23]; const float* b_out = (const float*)d_in[24];
    float* out = (float*)d_out;

    // workspace layout (bytes)
    char* ws = (char*)d_ws;
    unsigned short* wfrag = (unsigned short*)ws;                       // 1.5 MB @0
    unsigned long long* Spl = (unsigned long long*)(ws + 0x180000);    // 64 KB  (pay,tag)
    unsigned long long* Upl = (unsigned long long*)(ws + 0x190000);    // 384 KB (pay,tag)
    unsigned* prog = (unsigned*)(ws + 0x1F0000);                       // 2 KB progress flags
    unsigned* packdone = (unsigned*)(ws + 0x1F0800);                   // 4 B
    unsigned short* Ta_bf   = (unsigned short*)(ws + 0x200000);        // 4 MB [4096][512]
    unsigned short* hWcg_t  = (unsigned short*)(ws + 0x600000);        // 4 MB [32][512][128]
    unsigned short* hWc_t   = (unsigned short*)(ws + 0xA00000);        // 4 MB
    float* xgxs     = (float*)(ws + 0xE00000);                         // 8 MB [2048][1024]
    unsigned short* dh      = (unsigned short*)(ws + 0x1600000);       // 2 MB t-major [64*32][512]
    unsigned short* wpk     = (unsigned short*)(ws + 0x1800000);       // 32.75 MB packed W_out

    // zero tag planes + progress flags + packdone every launch
    hipMemsetAsync(ws + 0x180000, 0, 0x71000, stream);

    // K0+K1+K2 fused pre-kernel
    pre_kernel<<<896, 256, 0, stream>>>(
        hiddens, W_enc, Wc_g, Wc, b_enc, Ta_bf, hWcg_t, hWc_t,
        embed, target, Wi_g, Wi, bi_g, bh_g, bc_g, bi, bh, bc, xgxs,
        W_prev, Wh_g, Wh, wfrag);

    // K3+K4 fused: scan (blocks 0-31) + pack + tag-gated OUT gemm (32-255)
    fused_scan_out<<<256, 1024, 0, stream>>>(
        content, sentiment, b_prev, W_att, Ta_bf, hWcg_t, hWc_t,
        xgxs, wfrag, Spl, Upl, dh, prog, packdone, wpk, W_out, b_out, out);

    (void)in_sizes; (void)n_in; (void)out_size; (void)ws_size;
}